// Round 15
// baseline (169.408 us; speedup 1.0000x reference)
//
#include <hip/hip_runtime.h>

#define B_ 8
#define C_ 256
#define HW_ 2304
#define E_ 64
#define SB_ (C_*HW_)  // 589824 floats per batch
#define LOG2E_ 1.44269504088896340736f

typedef unsigned short u16;
typedef __attribute__((ext_vector_type(8))) __bf16 bf16x8;
typedef __attribute__((ext_vector_type(4))) float f32x4;
#define MFMA16(a,b,c) __builtin_amdgcn_mfma_f32_16x16x32_bf16(a,b,c,0,0,0)

// per-wave LDS write->read ordering (single-wave blocks; vmcnt untouched)
#define LDS_FENCE() do { asm volatile("s_waitcnt lgkmcnt(0)" ::: "memory"); \
                         __builtin_amdgcn_sched_barrier(0); } while(0)

// fp32 -> bf16 RNE via integer ops (compiler-schedulable scalar path)
static __device__ inline u16 f2bf(float x){
  unsigned u = __builtin_bit_cast(unsigned, x);
  u += 0x7FFFu + ((u >> 16) & 1u);
  return (u16)(u >> 16);
}
static __device__ inline float bf2f(u16 h){
  unsigned u = ((unsigned)h) << 16;
  return __builtin_bit_cast(float, u);
}

// Fragment-contiguous layouts (u16 units), lane = g*16 + l15:
//  Q/K:  (tile*2 + kc)*512 + lane*8 + u ; tile = b*144 + pos/16, value (pos=tile*16+l15, e=kc*32+g*8+u)
//  V:    ((b*72 + ic)*4 + es)*512 + lane*8 + u ; value (e=es*16+l15, i=ic*32+g*8+u)
//  attc: ((b*16 + jt)*8 + kc)*512 + lane*8 + u ; value (j=jt*16+l15, i=kc*32+g*8+u)
//  W:    ((mz*4 + m)*8 + kc)*512 + lane*8 + u  ; value (e=m*16+l15, c=kc*32+g*8+u)
// NOTE: K (mz==1) is pre-scaled by log2e so downstream softmax uses exp2.
// NOTE: V is rescaled in place by k_vscale: v'[e,i] = v[e,i]/l_i, so k_gs11 uses raw exp2.

struct KFrag { bf16x8 h0, h1, l0, l1; };
static __device__ __forceinline__ KFrag ldfrag(const u16* __restrict__ ph,
                                               const u16* __restrict__ pl,
                                               size_t tile, int lane){
  KFrag q;
  q.h0 = *(const bf16x8*)(ph + (tile*2+0)*512 + (size_t)lane*8);
  q.h1 = *(const bf16x8*)(ph + (tile*2+1)*512 + (size_t)lane*8);
  q.l0 = *(const bf16x8*)(pl + (tile*2+0)*512 + (size_t)lane*8);
  q.l1 = *(const bf16x8*)(pl + (tile*2+1)*512 + (size_t)lane*8);
  return q;
}

// ---- GAP: mean over HW per (b,c) ----
__global__ __launch_bounds__(256) void k_gap(const float* __restrict__ f, float* __restrict__ gap){
  int bc = blockIdx.x;
  const float* row = f + (size_t)bc * HW_;
  float s = 0.f;
  for (int i = threadIdx.x; i < HW_; i += 256) s += row[i];
  #pragma unroll
  for (int off = 32; off; off >>= 1) s += __shfl_down(s, off);
  __shared__ float red[4];
  int lane = threadIdx.x & 63, wv = threadIdx.x >> 6;
  if (lane == 0) red[wv] = s;
  __syncthreads();
  if (threadIdx.x == 0) gap[bc] = (red[0]+red[1]+red[2]+red[3]) * (1.0f/HW_);
}

// ---- conv1d(k=3)+sigmoid, rank-1 scores, softmax over i. Wave-parallel reductions. ----
__global__ __launch_bounds__(256) void k_attc3(const float* __restrict__ gap,
    const float* __restrict__ wq1, const float* __restrict__ bq1,
    const float* __restrict__ wk1, const float* __restrict__ bk1,
    u16* __restrict__ ath, u16* __restrict__ atl){
  int b = blockIdx.x >> 8;
  int j = blockIdx.x & 255;
  int i = threadIdx.x;
  const float* g = gap + b*C_;
  float gm1 = (i > 0)      ? g[i-1] : 0.f;
  float g0  = g[i];
  float gp1 = (i < C_-1)   ? g[i+1] : 0.f;
  float keyv = wk1[0]*gm1 + wk1[1]*g0 + wk1[2]*gp1 + bk1[0];
  keyv = 1.f/(1.f+__expf(-keyv));
  float qm1 = (j > 0)      ? g[j-1] : 0.f;
  float q0  = g[j];
  float qp1 = (j < C_-1)   ? g[j+1] : 0.f;
  float qv = wq1[0]*qm1 + wq1[1]*q0 + wq1[2]*qp1 + bq1[0];
  qv = 1.f/(1.f+__expf(-qv));
  float s = keyv * qv;
  __shared__ float red[8];
  int wv = i >> 6, ln = i & 63;
  float m = s;
  #pragma unroll
  for (int off = 32; off; off >>= 1) m = fmaxf(m, __shfl_xor(m, off));
  if (ln == 0) red[wv] = m;
  __syncthreads();
  float mx = fmaxf(fmaxf(red[0], red[1]), fmaxf(red[2], red[3]));
  float e = __expf(s - mx);
  float sm = e;
  #pragma unroll
  for (int off = 32; off; off >>= 1) sm += __shfl_xor(sm, off);
  if (ln == 0) red[4 + wv] = sm;
  __syncthreads();
  float sum = (red[4] + red[5]) + (red[6] + red[7]);
  float x = e / sum;
  u16 hb = f2bf(x);
  size_t o = (((size_t)b*16 + (j>>4))*8 + (i>>5))*512 + (((i&31)>>3)*16 + (j&15))*8 + (i&7);
  ath[o] = hb;
  atl[o] = f2bf(x - bf2f(hb));
}

// ---- convert wq2/wk2/wv2 -> bf16 hi/lo A-frag layout; K pre-scaled by log2e ----
__global__ __launch_bounds__(256) void k_wcvt(const float* __restrict__ wq,
    const float* __restrict__ wk, const float* __restrict__ wv,
    u16* __restrict__ wbh, u16* __restrict__ wbl){
  int n = blockIdx.x*256 + threadIdx.x;     // 0..49151
  int mz = n >> 14; int idx = n & 16383;
  int e = idx >> 8, c = idx & 255;
  const float* w = (mz==0) ? wq : ((mz==1) ? wk : wv);
  float x = w[idx] * ((mz==1) ? LOG2E_ : 1.0f);
  u16 hb = f2bf(x);
  size_t widx = (((size_t)mz*4 + (e>>4))*8 + (c>>5))*512 + (((c&31)>>3)*16 + (e&15))*8 + (c&7);
  wbh[widx] = hb;
  wbl[widx] = f2bf(x - bf2f(hb));
}

// ---- q/k/v projections via MFMA. 1 wave per (b, p-tile 16, matrix x e-half). ----
// grid (B, 144, 6): mz = z>>1, mh = z&1 (e-half). Scalar f2bf packing.
__global__ __launch_bounds__(64) void k_proj6(const float* __restrict__ f,
    const u16* __restrict__ wbh, const u16* __restrict__ wbl,
    const float* __restrict__ bq, const float* __restrict__ bk, const float* __restrict__ bv,
    u16* __restrict__ qh, u16* __restrict__ qlo,
    u16* __restrict__ kh, u16* __restrict__ klo,
    u16* __restrict__ vh, u16* __restrict__ vlo){
  int b = blockIdx.x; int p0 = blockIdx.y*16;
  int mz = blockIdx.z >> 1, mh = blockIdx.z & 1;
  int lane = threadIdx.x; int l15 = lane & 15, g = lane >> 4;
  const float* fb = f + (size_t)b*SB_ + p0 + l15;
  const u16* wh = wbh + (size_t)mz*16384;
  const u16* wl = wbl + (size_t)mz*16384;
  const float* bi = (mz==0) ? bq : ((mz==1) ? bk : bv);
  const float bsc = (mz==1) ? LOG2E_ : 1.0f;
  f32x4 c1[2], c2[2], c3[2];
  #pragma unroll
  for (int m = 0; m < 2; m++){
    c1[m] = (f32x4){0.f,0.f,0.f,0.f};
    c2[m] = (f32x4){0.f,0.f,0.f,0.f};
    c3[m] = (f32x4){0.f,0.f,0.f,0.f};
  }
  #pragma unroll
  for (int ks = 0; ks < 8; ks++){
    int cb = ks*32 + g*8;
    float fe[8];
    #pragma unroll
    for (int u = 0; u < 8; u++) fe[u] = fb[(size_t)(cb + u)*HW_];
    union { u16 u[8]; bf16x8 v; } FH, FL;
    #pragma unroll
    for (int u = 0; u < 8; u++){
      u16 hb = f2bf(fe[u]);
      FH.u[u] = hb;
      FL.u[u] = f2bf(fe[u] - bf2f(hb));
    }
    #pragma unroll
    for (int ml = 0; ml < 2; ml++){
      int m = mh*2 + ml;
      bf16x8 awh = *(const bf16x8*)(wh + ((size_t)m*8 + ks)*512 + (size_t)lane*8);
      bf16x8 awl = *(const bf16x8*)(wl + ((size_t)m*8 + ks)*512 + (size_t)lane*8);
      c1[ml] = MFMA16(awh, FH.v, c1[ml]);
      c2[ml] = MFMA16(awh, FL.v, c2[ml]);
      c3[ml] = MFMA16(awl, FH.v, c3[ml]);
    }
  }
  if (mz < 2){
    u16* ohb = (mz==0 ? qh : kh);
    u16* olb = (mz==0 ? qlo: klo);
    size_t tb = ((size_t)b*144 + blockIdx.y)*2;
    #pragma unroll
    for (int ml = 0; ml < 2; ml++){
      int m = mh*2 + ml;
      union { u16 u[4]; uint2 v2; } H, L;
      #pragma unroll
      for (int r = 0; r < 4; r++){
        int e = m*16 + g*4 + r;
        float x = c1[ml][r] + c2[ml][r] + c3[ml][r] + bi[e]*bsc;
        u16 hb = f2bf(x);
        H.u[r] = hb;
        L.u[r] = f2bf(x - bf2f(hb));
      }
      int kc = mh;
      int gc = ml*2 + (g >> 1);
      int ub = (g & 1)*4;
      size_t idx = (tb + kc)*512 + (gc*16 + l15)*8 + ub;
      *(uint2*)(ohb + idx) = H.v2;
      *(uint2*)(olb + idx) = L.v2;
    }
  } else {
    int ic = blockIdx.y >> 1;
    int half = blockIdx.y & 1;
    int gg = half*2 + (l15 >> 3);
    int uu = l15 & 7;
    size_t vb0 = ((size_t)b*72 + ic)*4;
    #pragma unroll
    for (int ml = 0; ml < 2; ml++){
      int m = mh*2 + ml;
      #pragma unroll
      for (int r = 0; r < 4; r++){
        int e = m*16 + g*4 + r;
        float x = c1[ml][r] + c2[ml][r] + c3[ml][r] + bi[e];
        u16 hb = f2bf(x);
        size_t idx = (vb0 + m)*512 + (gg*16 + (g*4 + r))*8 + uu;
        vh[idx] = hb;
        vlo[idx] = f2bf(x - bf2f(hb));
      }
    }
  }
}

// ---- pass 1: partial row sums l_i = sum_j exp2(s'), i-tile 32, j range 256 (16 tiles). ----
// grid (B, 72, 9)
__global__ __launch_bounds__(64,2) void k_stats6(
    const u16* __restrict__ qh, const u16* __restrict__ qlo,
    const u16* __restrict__ kh, const u16* __restrict__ klo,
    float* __restrict__ lpart){
  int b = blockIdx.x; int it0 = blockIdx.y; int jz = blockIdx.z;
  int lane = threadIdx.x; int l15 = lane & 15, g = lane >> 4;
  const size_t b144 = (size_t)b*144;
  KFrag kf0 = ldfrag(kh, klo, b144 + it0*2,     lane);
  KFrag kf1 = ldfrag(kh, klo, b144 + it0*2 + 1, lane);
  float lsum[8];
  #pragma unroll
  for (int x = 0; x < 8; x++) lsum[x] = 0.f;
  size_t qb0 = b144 + jz*16;
  #pragma unroll
  for (int t = 0; t < 16; t++){
    KFrag q = ldfrag(qh, qlo, qb0 + t, lane);
    #pragma unroll
    for (int isub = 0; isub < 2; isub++){
      const KFrag& kf = isub ? kf1 : kf0;
      f32x4 c1 = {0.f,0.f,0.f,0.f}, c2 = {0.f,0.f,0.f,0.f}, c3 = {0.f,0.f,0.f,0.f};
      c1 = MFMA16(kf.h0, q.h0, c1);
      c2 = MFMA16(kf.h0, q.l0, c2);
      c3 = MFMA16(kf.l0, q.h0, c3);
      c1 = MFMA16(kf.h1, q.h1, c1);
      c2 = MFMA16(kf.h1, q.l1, c2);
      c3 = MFMA16(kf.l1, q.h1, c3);
      #pragma unroll
      for (int r = 0; r < 4; r++) lsum[isub*4+r] += __builtin_exp2f(c1[r] + c2[r] + c3[r]);
    }
  }
  #pragma unroll
  for (int mk = 1; mk < 16; mk <<= 1){
    #pragma unroll
    for (int x = 0; x < 8; x++) lsum[x] += __shfl_xor(lsum[x], mk);
  }
  if (l15 == 0){
    float* lp = lpart + ((size_t)jz*B_ + b)*HW_ + it0*32;
    #pragma unroll
    for (int isub = 0; isub < 2; isub++)
      #pragma unroll
      for (int r = 0; r < 4; r++) lp[isub*16 + g*4 + r] = lsum[isub*4+r];
  }
}

// ---- rl = 1/(sum of 9 partials) ----
__global__ __launch_bounds__(256) void k_rli9(const float* __restrict__ lpart, float* __restrict__ rl){
  int i = blockIdx.x*256 + threadIdx.x;
  const int BH = B_*HW_;
  float s = 0.f;
  #pragma unroll
  for (int p = 0; p < 9; p++) s += lpart[(size_t)p*BH + i];
  rl[i] = 1.0f / s;
}

// ---- v' = v * rl_i, in place (hi/lo re-split). 576 blocks x 256 threads. ----
__global__ __launch_bounds__(256) void k_vscale(const float* __restrict__ rl,
    u16* __restrict__ vh, u16* __restrict__ vlo){
  int flat = blockIdx.x*256 + threadIdx.x;   // 0..147455
  int lane = flat & 63;
  int slot = flat >> 6;                       // (b*72+ic)*4+es
  int b = slot / 288;
  int rem = slot - b*288;
  int ic = rem >> 2;
  int g = lane >> 4;
  const float* rb = rl + b*HW_ + ic*32 + g*8;
  f32x4 r0 = *(const f32x4*)rb;
  f32x4 r1 = *(const f32x4*)(rb + 4);
  u16* ph = vh  + (size_t)slot*512 + (size_t)lane*8;
  u16* pl = vlo + (size_t)slot*512 + (size_t)lane*8;
  union { u16 u[8]; uint4 v; } H, L;
  H.v = *(const uint4*)ph;
  L.v = *(const uint4*)pl;
  #pragma unroll
  for (int u = 0; u < 8; u++){
    float v = bf2f(H.u[u]) + bf2f(L.u[u]);
    float r = (u < 4) ? r0[u] : r1[u-4];
    float x = v * r;
    u16 hb = f2bf(x);
    H.u[u] = hb;
    L.u[u] = f2bf(x - bf2f(hb));
  }
  *(uint4*)ph = H.v;
  *(uint4*)pl = L.v;
}

// ---- pass 2: partial GS, j-tile 32, i range 256 (8 chunks). V pre-scaled -> raw exp2. ----
// grid (B, 72, 9). launch_bounds(64,5) pins VGPR <= 102 -> 5 waves/SIMD.
__global__ __launch_bounds__(64,5) void k_gs11(
    const u16* __restrict__ qh, const u16* __restrict__ qlo,
    const u16* __restrict__ kh, const u16* __restrict__ klo,
    const u16* __restrict__ vh, const u16* __restrict__ vlo,
    float* __restrict__ gsp){
  int b = blockIdx.x; int jt0 = blockIdx.y; int iz = blockIdx.z;
  int j0 = jt0*32;
  int lane = threadIdx.x; int l15 = lane & 15, g = lane >> 4;
  __shared__ __align__(16) char smem[10240];
  const size_t b144 = (size_t)b*144;
  KFrag qf0 = ldfrag(qh, qlo, b144 + jt0*2,     lane);
  KFrag qf1 = ldfrag(qh, qlo, b144 + jt0*2 + 1, lane);
  f32x4 gacc[2][4];
  #pragma unroll
  for (int jt = 0; jt < 2; jt++)
    #pragma unroll
    for (int es = 0; es < 4; es++) gacc[jt][es] = (f32x4){0.f,0.f,0.f,0.f};
  #pragma unroll 2
  for (int ic = 0; ic < 8; ic++){
    // V A-frags (dense 1KB loads), issued early, consumed after the fence
    bf16x8 vfh[4], vfl[4];
    size_t vc = ((size_t)b*72 + iz*8 + ic)*4;
    #pragma unroll
    for (int es = 0; es < 4; es++){
      vfh[es] = *(const bf16x8*)(vh  + (vc+es)*512 + (size_t)lane*8);
      vfl[es] = *(const bf16x8*)(vlo + (vc+es)*512 + (size_t)lane*8);
    }
    char* PhB = smem + (ic & 1)*2560;
    char* PlB = smem + 5120 + (ic & 1)*2560;
    #pragma unroll
    for (int msub = 0; msub < 2; msub++){
      KFrag kf = ldfrag(kh, klo, b144 + iz*16 + ic*2 + msub, lane);
      #pragma unroll
      for (int jt = 0; jt < 2; jt++){
        const KFrag& qf = jt ? qf1 : qf0;
        f32x4 c1 = {0.f,0.f,0.f,0.f}, c2 = {0.f,0.f,0.f,0.f}, c3 = {0.f,0.f,0.f,0.f};
        c1 = MFMA16(kf.h0, qf.h0, c1);
        c2 = MFMA16(kf.h0, qf.l0, c2);
        c3 = MFMA16(kf.l0, qf.h0, c3);
        c1 = MFMA16(kf.h1, qf.h1, c1);
        c2 = MFMA16(kf.h1, qf.l1, c2);
        c3 = MFMA16(kf.l1, qf.h1, c3);
        union { u16 u[4]; uint2 v2; } PH, PL;
        #pragma unroll
        for (int r = 0; r < 4; r++){
          float x = __builtin_exp2f(c1[r] + c2[r] + c3[r]);
          u16 hb = f2bf(x);
          float hf = bf2f(hb);
          PH.u[r] = hb;
          PL.u[r] = f2bf(x - hf);
        }
        *(uint2*)(PhB + (jt*16 + l15)*80 + msub*32 + g*8) = PH.v2;
        *(uint2*)(PlB + (jt*16 + l15)*80 + msub*32 + g*8) = PL.v2;
      }
    }
    LDS_FENCE();
    #pragma unroll
    for (int jt = 0; jt < 2; jt++){
      bf16x8 pf_h = *(const bf16x8*)(PhB + (jt*16 + l15)*80 + g*16);
      bf16x8 pf_l = *(const bf16x8*)(PlB + (jt*16 + l15)*80 + g*16);
      #pragma unroll
      for (int es = 0; es < 4; es++){
        gacc[jt][es] = MFMA16(vfh[es], pf_h, gacc[jt][es]);
        gacc[jt][es] = MFMA16(vfh[es], pf_l, gacc[jt][es]);
        gacc[jt][es] = MFMA16(vfl[es], pf_h, gacc[jt][es]);
      }
    }
  }
  // ---- epilogue: transpose gacc through LDS -> full-line dwordx4 stores ----
  LDS_FENCE();
  float* GT = (float*)smem;
  #pragma unroll
  for (int jt = 0; jt < 2; jt++)
    #pragma unroll
    for (int es = 0; es < 4; es++)
      #pragma unroll
      for (int r = 0; r < 4; r++)
        GT[(es*16 + g*4 + r)*32 + jt*16 + l15] = gacc[jt][es][r];
  LDS_FENCE();
  float* gb = gsp + ((size_t)iz*B_ + b)*E_*HW_;
  #pragma unroll
  for (int itx = 0; itx < 8; itx++){
    int n = (itx*64 + lane)*4;
    f32x4 vv = *(const f32x4*)&GT[n];
    int e = n >> 5, jj = n & 31;
    *(f32x4*)&gb[(size_t)e*HW_ + j0 + jj] = vv;
  }
}

// ---- gs = sum of 9 gsp partials ----
__global__ __launch_bounds__(256) void k_gsum9(const float* __restrict__ gsp, float* __restrict__ gs){
  const size_t N = (size_t)B_*E_*HW_;
  size_t n = ((size_t)blockIdx.x*256 + threadIdx.x)*4;
  f32x4 s = *(const f32x4*)(gsp + n);
  #pragma unroll
  for (int p = 1; p < 9; p++) s += *(const f32x4*)(gsp + (size_t)p*N + n);
  *(f32x4*)(gs + n) = s;
}

// ---- gsout[c,s] = sum_e watt[c,e]*gs[e,s] + batt[c]; 32 c-rows/block (half the gs re-reads) ----
__global__ __launch_bounds__(256) void k_gsout3(const float* __restrict__ gs,
    const float* __restrict__ watt, const float* __restrict__ batt,
    float* __restrict__ gsout){
  int b = blockIdx.x; int sc = blockIdx.y; int cc0 = blockIdx.z * 32;
  int s = sc*256 + threadIdx.x;
  const float* gb = gs + (size_t)b*E_*HW_ + s;
  float acc[32];
  #pragma unroll
  for (int x = 0; x < 32; x++) acc[x] = 0.f;
  for (int e = 0; e < E_; e++){
    float gv = gb[(size_t)e*HW_];
    #pragma unroll
    for (int x = 0; x < 32; x++) acc[x] += watt[(cc0+x)*E_ + e] * gv;   // uniform -> s_load
  }
  float* ob = gsout + (size_t)b*SB_ + (size_t)cc0*HW_ + s;
  #pragma unroll
  for (int x = 0; x < 32; x++) ob[(size_t)x*HW_] = acc[x] + batt[cc0 + x];
}

// ---- final: gc via MFMA, fused out = f*gc*(gsout+1). grid (B, 144, 4): 4 j-tiles/wave ----
__global__ __launch_bounds__(64) void k_final3(const float* __restrict__ f,
    const u16* __restrict__ ath, const u16* __restrict__ atl,
    float* __restrict__ inout){
  int b = blockIdx.x; int s0 = blockIdx.y*16; int z = blockIdx.z;
  int lane = threadIdx.x; int l15 = lane & 15, g = lane >> 4;
  const float* fb = f + (size_t)b*SB_;
  bf16x8 Ah[8], Al[8];
  const float* arow = fb + (size_t)(s0 + l15)*C_;
  #pragma unroll
  for (int ks = 0; ks < 8; ks++){
    int cbase = ks*32 + g*8;
    float4 f4a = *(const float4*)&arow[cbase];
    float4 f4b = *(const float4*)&arow[cbase + 4];
    float fe[8] = {f4a.x, f4a.y, f4a.z, f4a.w, f4b.x, f4b.y, f4b.z, f4b.w};
    union { u16 u[8]; bf16x8 v; } H, L;
    #pragma unroll
    for (int e = 0; e < 8; e++){
      u16 hb = f2bf(fe[e]);
      H.u[e] = hb;
      L.u[e] = f2bf(fe[e] - bf2f(hb));
    }
    Ah[ks] = H.v; Al[ks] = L.v;
  }
  const u16* abz_h = ath + (size_t)b*65536;
  const u16* abz_l = atl + (size_t)b*65536;
  f32x4 acc[4];
  #pragma unroll
  for (int q = 0; q < 4; q++) acc[q] = (f32x4){0.f,0.f,0.f,0.f};
  #pragma unroll
  for (int q = 0; q < 4; q++){
    int jt = z*4 + q;
    #pragma unroll
    for (int ks = 0; ks < 8; ks++){
      bf16x8 Bh = *(const bf16x8*)(abz_h + ((size_t)jt*8 + ks)*512 + (size_t)lane*8);
      bf16x8 Bl = *(const bf16x8*)(abz_l + ((size_t)jt*8 + ks)*512 + (size_t)lane*8);
      acc[q] = MFMA16(Ah[ks], Bh, acc[q]);
      acc[q] = MFMA16(Ah[ks], Bl, acc[q]);
      acc[q] = MFMA16(Al[ks], Bh, acc[q]);
    }
  }
  float* ob = inout + (size_t)b*SB_;
  #pragma unroll
  for (int q = 0; q < 4; q++){
    #pragma unroll
    for (int r = 0; r < 4; r++){
      int p = s0 + g*4 + r;
      int j = (z*4+q)*16 + l15;
      size_t n = (size_t)p*C_ + j;
      float fx = fb[n];
      float gso = ob[n];
      ob[n] = acc[q][r] * fx * (gso + 1.f);
    }
  }
}

extern "C" void kernel_launch(void* const* d_in, const int* in_sizes, int n_in,
                              void* d_out, int out_size, void* d_ws, size_t ws_size,
                              hipStream_t stream){
  const float* f    = (const float*)d_in[0];
  const float* wq1  = (const float*)d_in[1];
  const float* bq1  = (const float*)d_in[2];
  const float* wk1  = (const float*)d_in[3];
  const float* bk1  = (const float*)d_in[4];
  const float* wq2  = (const float*)d_in[5];
  const float* bq2  = (const float*)d_in[6];
  const float* wk2  = (const float*)d_in[7];
  const float* bk2  = (const float*)d_in[8];
  const float* wv2  = (const float*)d_in[9];
  const float* bv2  = (const float*)d_in[10];
  const float* watt = (const float*)d_in[11];
  const float* batt = (const float*)d_in[12];
  float* out = (float*)d_out;
  char* W = (char*)d_ws;

  // byte offsets (16B aligned); total = 64,380,928 B (~61.4 MiB)
  float* gap   = (float*)(W + 0);          //     8192
  u16*   ath   = (u16*)  (W + 8192);       //  1048576
  u16*   atl   = (u16*)  (W + 1056768);    //  1048576
  float* lpart = (float*)(W + 2105344);    //   663552 (9 x B x HW)
  float* rl    = (float*)(W + 2768896);    //    73728
  float* gsp   = (float*)(W + 2842624);    // 42467328 (9 x B x E x HW)
  float* gs    = (float*)(W + 45309952);   //  4718592
  u16* qh  = (u16*)(W + 50028544);         //  2359296 each below
  u16* qlo = (u16*)(W + 52387840);
  u16* kh  = (u16*)(W + 54747136);
  u16* klo = (u16*)(W + 57106432);
  u16* vh  = (u16*)(W + 59465728);
  u16* vlo = (u16*)(W + 61825024);
  u16* wbh = (u16*)(W + 64184320);         //    98304
  u16* wbl = (u16*)(W + 64282624);         //    98304

  k_gap   <<<B_*C_,             256, 0, stream>>>(f, gap);
  k_attc3 <<<B_*C_,             256, 0, stream>>>(gap, wq1, bq1, wk1, bk1, ath, atl);
  k_wcvt  <<<192,               256, 0, stream>>>(wq2, wk2, wv2, wbh, wbl);
  k_proj6 <<<dim3(B_, 144, 6),   64, 0, stream>>>(f, wbh, wbl, bq2, bk2, bv2,
                                                  qh, qlo, kh, klo, vh, vlo);
  k_stats6<<<dim3(B_, 72, 9),    64, 0, stream>>>(qh, qlo, kh, klo, lpart);
  k_rli9  <<<B_*HW_/256,        256, 0, stream>>>(lpart, rl);
  k_vscale<<<576,               256, 0, stream>>>(rl, vh, vlo);
  k_gs11  <<<dim3(B_, 72, 9),    64, 0, stream>>>(qh, qlo, kh, klo, vh, vlo, gsp);
  k_gsum9 <<<B_*E_*HW_/1024,    256, 0, stream>>>(gsp, gs);
  k_gsout3<<<dim3(B_, 9, 8),    256, 0, stream>>>(gs, watt, batt, out);
  k_final3<<<dim3(B_, 144, 4),   64, 0, stream>>>(f, ath, atl, out);
}

// Round 16
// 167.669 us; speedup vs baseline: 1.0104x; 1.0104x over previous
//
#include <hip/hip_runtime.h>

#define B_ 8
#define C_ 256
#define HW_ 2304
#define E_ 64
#define SB_ (C_*HW_)  // 589824 floats per batch
#define LOG2E_ 1.44269504088896340736f

typedef unsigned short u16;
typedef __attribute__((ext_vector_type(8))) __bf16 bf16x8;
typedef __attribute__((ext_vector_type(4))) float f32x4;
#define MFMA16(a,b,c) __builtin_amdgcn_mfma_f32_16x16x32_bf16(a,b,c,0,0,0)

// epilogue-only LDS ordering (single-wave blocks)
#define LDS_FENCE() do { asm volatile("s_waitcnt lgkmcnt(0)" ::: "memory"); \
                         __builtin_amdgcn_sched_barrier(0); } while(0)

// fp32 -> bf16 RNE via integer ops (compiler-schedulable scalar path)
static __device__ inline u16 f2bf(float x){
  unsigned u = __builtin_bit_cast(unsigned, x);
  u += 0x7FFFu + ((u >> 16) & 1u);
  return (u16)(u >> 16);
}
static __device__ inline float bf2f(u16 h){
  unsigned u = ((unsigned)h) << 16;
  return __builtin_bit_cast(float, u);
}

// Fragment-contiguous layouts (u16 units), lane = g*16 + l15:
//  Q/K:  (tile*2 + kc)*512 + lane*8 + u ; tile = b*144 + pos/16, value (pos=tile*16+l15, e=kc*32+g*8+u)
//  V:    ((b*72 + ic)*4 + es)*512 + lane*8 + u ; value (e=es*16+l15, i=ic*32+g*8+u)
//  attc: ((b*16 + jt)*8 + kc)*512 + lane*8 + u ; value (j=jt*16+l15, i=kc*32+g*8+u)
//  W:    ((mz*4 + m)*8 + kc)*512 + lane*8 + u  ; value (e=m*16+l15, c=kc*32+g*8+u)
// NOTE: K (mz==1) is pre-scaled by log2e so downstream softmax uses exp2.
// NOTE: V is rescaled in place by k_vscale: v'[e,i] = v[e,i]/l_i, so k_gs13 uses raw exp2.
// NOTE: attc stored hi-only (softmax columns sum to 1 -> bf16-only error <= ~2e-3).

struct KFrag { bf16x8 h0, h1, l0, l1; };
static __device__ __forceinline__ KFrag ldfrag(const u16* __restrict__ ph,
                                               const u16* __restrict__ pl,
                                               size_t tile, int lane){
  KFrag q;
  q.h0 = *(const bf16x8*)(ph + (tile*2+0)*512 + (size_t)lane*8);
  q.h1 = *(const bf16x8*)(ph + (tile*2+1)*512 + (size_t)lane*8);
  q.l0 = *(const bf16x8*)(pl + (tile*2+0)*512 + (size_t)lane*8);
  q.l1 = *(const bf16x8*)(pl + (tile*2+1)*512 + (size_t)lane*8);
  return q;
}

// ---- GAP: mean over HW per (b,c) ----
__global__ __launch_bounds__(256) void k_gap(const float* __restrict__ f, float* __restrict__ gap){
  int bc = blockIdx.x;
  const float* row = f + (size_t)bc * HW_;
  float s = 0.f;
  for (int i = threadIdx.x; i < HW_; i += 256) s += row[i];
  #pragma unroll
  for (int off = 32; off; off >>= 1) s += __shfl_down(s, off);
  __shared__ float red[4];
  int lane = threadIdx.x & 63, wv = threadIdx.x >> 6;
  if (lane == 0) red[wv] = s;
  __syncthreads();
  if (threadIdx.x == 0) gap[bc] = (red[0]+red[1]+red[2]+red[3]) * (1.0f/HW_);
}

// ---- conv1d(k=3)+sigmoid, rank-1 scores, softmax over i -> bf16 (hi only) B-frag layout ----
__global__ __launch_bounds__(256) void k_attc4(const float* __restrict__ gap,
    const float* __restrict__ wq1, const float* __restrict__ bq1,
    const float* __restrict__ wk1, const float* __restrict__ bk1,
    u16* __restrict__ ath){
  int b = blockIdx.x >> 8;
  int j = blockIdx.x & 255;
  int i = threadIdx.x;
  const float* g = gap + b*C_;
  float gm1 = (i > 0)      ? g[i-1] : 0.f;
  float g0  = g[i];
  float gp1 = (i < C_-1)   ? g[i+1] : 0.f;
  float keyv = wk1[0]*gm1 + wk1[1]*g0 + wk1[2]*gp1 + bk1[0];
  keyv = 1.f/(1.f+__expf(-keyv));
  float qm1 = (j > 0)      ? g[j-1] : 0.f;
  float q0  = g[j];
  float qp1 = (j < C_-1)   ? g[j+1] : 0.f;
  float qv = wq1[0]*qm1 + wq1[1]*q0 + wq1[2]*qp1 + bq1[0];
  qv = 1.f/(1.f+__expf(-qv));
  float s = keyv * qv;
  __shared__ float red[8];
  int wv = i >> 6, ln = i & 63;
  float m = s;
  #pragma unroll
  for (int off = 32; off; off >>= 1) m = fmaxf(m, __shfl_xor(m, off));
  if (ln == 0) red[wv] = m;
  __syncthreads();
  float mx = fmaxf(fmaxf(red[0], red[1]), fmaxf(red[2], red[3]));
  float e = __expf(s - mx);
  float sm = e;
  #pragma unroll
  for (int off = 32; off; off >>= 1) sm += __shfl_xor(sm, off);
  if (ln == 0) red[4 + wv] = sm;
  __syncthreads();
  float sum = (red[4] + red[5]) + (red[6] + red[7]);
  float x = e / sum;
  size_t o = (((size_t)b*16 + (j>>4))*8 + (i>>5))*512 + (((i&31)>>3)*16 + (j&15))*8 + (i&7);
  ath[o] = f2bf(x);
}

// ---- convert wq2/wk2/wv2 -> bf16 hi/lo A-frag layout; K pre-scaled by log2e ----
__global__ __launch_bounds__(256) void k_wcvt(const float* __restrict__ wq,
    const float* __restrict__ wk, const float* __restrict__ wv,
    u16* __restrict__ wbh, u16* __restrict__ wbl){
  int n = blockIdx.x*256 + threadIdx.x;     // 0..49151
  int mz = n >> 14; int idx = n & 16383;
  int e = idx >> 8, c = idx & 255;
  const float* w = (mz==0) ? wq : ((mz==1) ? wk : wv);
  float x = w[idx] * ((mz==1) ? LOG2E_ : 1.0f);
  u16 hb = f2bf(x);
  size_t widx = (((size_t)mz*4 + (e>>4))*8 + (c>>5))*512 + (((c&31)>>3)*16 + (e&15))*8 + (c&7);
  wbh[widx] = hb;
  wbl[widx] = f2bf(x - bf2f(hb));
}

// ---- q/k/v projections via MFMA. 1 wave per (b, p-tile 16, matrix x e-half). ----
__global__ __launch_bounds__(64) void k_proj6(const float* __restrict__ f,
    const u16* __restrict__ wbh, const u16* __restrict__ wbl,
    const float* __restrict__ bq, const float* __restrict__ bk, const float* __restrict__ bv,
    u16* __restrict__ qh, u16* __restrict__ qlo,
    u16* __restrict__ kh, u16* __restrict__ klo,
    u16* __restrict__ vh, u16* __restrict__ vlo){
  int b = blockIdx.x; int p0 = blockIdx.y*16;
  int mz = blockIdx.z >> 1, mh = blockIdx.z & 1;
  int lane = threadIdx.x; int l15 = lane & 15, g = lane >> 4;
  const float* fb = f + (size_t)b*SB_ + p0 + l15;
  const u16* wh = wbh + (size_t)mz*16384;
  const u16* wl = wbl + (size_t)mz*16384;
  const float* bi = (mz==0) ? bq : ((mz==1) ? bk : bv);
  const float bsc = (mz==1) ? LOG2E_ : 1.0f;
  f32x4 c1[2], c2[2], c3[2];
  #pragma unroll
  for (int m = 0; m < 2; m++){
    c1[m] = (f32x4){0.f,0.f,0.f,0.f};
    c2[m] = (f32x4){0.f,0.f,0.f,0.f};
    c3[m] = (f32x4){0.f,0.f,0.f,0.f};
  }
  #pragma unroll
  for (int ks = 0; ks < 8; ks++){
    int cb = ks*32 + g*8;
    float fe[8];
    #pragma unroll
    for (int u = 0; u < 8; u++) fe[u] = fb[(size_t)(cb + u)*HW_];
    union { u16 u[8]; bf16x8 v; } FH, FL;
    #pragma unroll
    for (int u = 0; u < 8; u++){
      u16 hb = f2bf(fe[u]);
      FH.u[u] = hb;
      FL.u[u] = f2bf(fe[u] - bf2f(hb));
    }
    #pragma unroll
    for (int ml = 0; ml < 2; ml++){
      int m = mh*2 + ml;
      bf16x8 awh = *(const bf16x8*)(wh + ((size_t)m*8 + ks)*512 + (size_t)lane*8);
      bf16x8 awl = *(const bf16x8*)(wl + ((size_t)m*8 + ks)*512 + (size_t)lane*8);
      c1[ml] = MFMA16(awh, FH.v, c1[ml]);
      c2[ml] = MFMA16(awh, FL.v, c2[ml]);
      c3[ml] = MFMA16(awl, FH.v, c3[ml]);
    }
  }
  if (mz < 2){
    u16* ohb = (mz==0 ? qh : kh);
    u16* olb = (mz==0 ? qlo: klo);
    size_t tb = ((size_t)b*144 + blockIdx.y)*2;
    #pragma unroll
    for (int ml = 0; ml < 2; ml++){
      int m = mh*2 + ml;
      union { u16 u[4]; uint2 v2; } H, L;
      #pragma unroll
      for (int r = 0; r < 4; r++){
        int e = m*16 + g*4 + r;
        float x = c1[ml][r] + c2[ml][r] + c3[ml][r] + bi[e]*bsc;
        u16 hb = f2bf(x);
        H.u[r] = hb;
        L.u[r] = f2bf(x - bf2f(hb));
      }
      int kc = mh;
      int gc = ml*2 + (g >> 1);
      int ub = (g & 1)*4;
      size_t idx = (tb + kc)*512 + (gc*16 + l15)*8 + ub;
      *(uint2*)(ohb + idx) = H.v2;
      *(uint2*)(olb + idx) = L.v2;
    }
  } else {
    int ic = blockIdx.y >> 1;
    int half = blockIdx.y & 1;
    int gg = half*2 + (l15 >> 3);
    int uu = l15 & 7;
    size_t vb0 = ((size_t)b*72 + ic)*4;
    #pragma unroll
    for (int ml = 0; ml < 2; ml++){
      int m = mh*2 + ml;
      #pragma unroll
      for (int r = 0; r < 4; r++){
        int e = m*16 + g*4 + r;
        float x = c1[ml][r] + c2[ml][r] + c3[ml][r] + bi[e];
        u16 hb = f2bf(x);
        size_t idx = (vb0 + m)*512 + (gg*16 + (g*4 + r))*8 + uu;
        vh[idx] = hb;
        vlo[idx] = f2bf(x - bf2f(hb));
      }
    }
  }
}

// ---- pass 1: partial row sums l_i = sum_j exp2(s'), i-tile 32, j range 256 (16 tiles). ----
// grid (B, 72, 9)
__global__ __launch_bounds__(64,2) void k_stats6(
    const u16* __restrict__ qh, const u16* __restrict__ qlo,
    const u16* __restrict__ kh, const u16* __restrict__ klo,
    float* __restrict__ lpart){
  int b = blockIdx.x; int it0 = blockIdx.y; int jz = blockIdx.z;
  int lane = threadIdx.x; int l15 = lane & 15, g = lane >> 4;
  const size_t b144 = (size_t)b*144;
  KFrag kf0 = ldfrag(kh, klo, b144 + it0*2,     lane);
  KFrag kf1 = ldfrag(kh, klo, b144 + it0*2 + 1, lane);
  float lsum[8];
  #pragma unroll
  for (int x = 0; x < 8; x++) lsum[x] = 0.f;
  size_t qb0 = b144 + jz*16;
  #pragma unroll
  for (int t = 0; t < 16; t++){
    KFrag q = ldfrag(qh, qlo, qb0 + t, lane);
    #pragma unroll
    for (int isub = 0; isub < 2; isub++){
      const KFrag& kf = isub ? kf1 : kf0;
      f32x4 c1 = {0.f,0.f,0.f,0.f}, c2 = {0.f,0.f,0.f,0.f}, c3 = {0.f,0.f,0.f,0.f};
      c1 = MFMA16(kf.h0, q.h0, c1);
      c2 = MFMA16(kf.h0, q.l0, c2);
      c3 = MFMA16(kf.l0, q.h0, c3);
      c1 = MFMA16(kf.h1, q.h1, c1);
      c2 = MFMA16(kf.h1, q.l1, c2);
      c3 = MFMA16(kf.l1, q.h1, c3);
      #pragma unroll
      for (int r = 0; r < 4; r++) lsum[isub*4+r] += __builtin_exp2f(c1[r] + c2[r] + c3[r]);
    }
  }
  #pragma unroll
  for (int mk = 1; mk < 16; mk <<= 1){
    #pragma unroll
    for (int x = 0; x < 8; x++) lsum[x] += __shfl_xor(lsum[x], mk);
  }
  if (l15 == 0){
    float* lp = lpart + ((size_t)jz*B_ + b)*HW_ + it0*32;
    #pragma unroll
    for (int isub = 0; isub < 2; isub++)
      #pragma unroll
      for (int r = 0; r < 4; r++) lp[isub*16 + g*4 + r] = lsum[isub*4+r];
  }
}

// ---- rl = 1/(sum of 9 partials) ----
__global__ __launch_bounds__(256) void k_rli9(const float* __restrict__ lpart, float* __restrict__ rl){
  int i = blockIdx.x*256 + threadIdx.x;
  const int BH = B_*HW_;
  float s = 0.f;
  #pragma unroll
  for (int p = 0; p < 9; p++) s += lpart[(size_t)p*BH + i];
  rl[i] = 1.0f / s;
}

// ---- v' = v * rl_i, in place (hi/lo re-split). 576 blocks x 256 threads. ----
__global__ __launch_bounds__(256) void k_vscale(const float* __restrict__ rl,
    u16* __restrict__ vh, u16* __restrict__ vlo){
  int flat = blockIdx.x*256 + threadIdx.x;   // 0..147455
  int lane = flat & 63;
  int slot = flat >> 6;                       // (b*72+ic)*4+es
  int b = slot / 288;
  int rem = slot - b*288;
  int ic = rem >> 2;
  int g = lane >> 4;
  const float* rb = rl + b*HW_ + ic*32 + g*8;
  f32x4 r0 = *(const f32x4*)rb;
  f32x4 r1 = *(const f32x4*)(rb + 4);
  u16* ph = vh  + (size_t)slot*512 + (size_t)lane*8;
  u16* pl = vlo + (size_t)slot*512 + (size_t)lane*8;
  union { u16 u[8]; uint4 v; } H, L;
  H.v = *(const uint4*)ph;
  L.v = *(const uint4*)pl;
  #pragma unroll
  for (int u = 0; u < 8; u++){
    float v = bf2f(H.u[u]) + bf2f(L.u[u]);
    float r = (u < 4) ? r0[u] : r1[u-4];
    float x = v * r;
    u16 hb = f2bf(x);
    H.u[u] = hb;
    L.u[u] = f2bf(x - bf2f(hb));
  }
  *(uint4*)ph = H.v;
  *(uint4*)pl = L.v;
}

// ---- pass 2: partial GS, j-tile 32, i range 256 (8 chunks). No inner-loop fences. ----
// grid (B, 72, 9). Single-wave LDS write->read is pipe-ordered; compiler keeps
// may-alias order and inserts lgkmcnt for data deps -> free to pipeline across chunks.
__global__ __launch_bounds__(64) void k_gs13(
    const u16* __restrict__ qh, const u16* __restrict__ qlo,
    const u16* __restrict__ kh, const u16* __restrict__ klo,
    const u16* __restrict__ vh, const u16* __restrict__ vlo,
    float* __restrict__ gsp){
  int b = blockIdx.x; int jt0 = blockIdx.y; int iz = blockIdx.z;
  int j0 = jt0*32;
  int lane = threadIdx.x; int l15 = lane & 15, g = lane >> 4;
  __shared__ __align__(16) char smem[10240];
  const size_t b144 = (size_t)b*144;
  KFrag qf0 = ldfrag(qh, qlo, b144 + jt0*2,     lane);
  KFrag qf1 = ldfrag(qh, qlo, b144 + jt0*2 + 1, lane);
  f32x4 gacc[2][4];
  #pragma unroll
  for (int jt = 0; jt < 2; jt++)
    #pragma unroll
    for (int es = 0; es < 4; es++) gacc[jt][es] = (f32x4){0.f,0.f,0.f,0.f};
  #pragma unroll 2
  for (int ic = 0; ic < 8; ic++){
    bf16x8 vfh[4], vfl[4];
    size_t vc = ((size_t)b*72 + iz*8 + ic)*4;
    #pragma unroll
    for (int es = 0; es < 4; es++){
      vfh[es] = *(const bf16x8*)(vh  + (vc+es)*512 + (size_t)lane*8);
      vfl[es] = *(const bf16x8*)(vlo + (vc+es)*512 + (size_t)lane*8);
    }
    char* PhB = smem + (ic & 1)*2560;
    char* PlB = smem + 5120 + (ic & 1)*2560;
    #pragma unroll
    for (int msub = 0; msub < 2; msub++){
      KFrag kf = ldfrag(kh, klo, b144 + iz*16 + ic*2 + msub, lane);
      #pragma unroll
      for (int jt = 0; jt < 2; jt++){
        const KFrag& qf = jt ? qf1 : qf0;
        f32x4 c1 = {0.f,0.f,0.f,0.f}, c2 = {0.f,0.f,0.f,0.f}, c3 = {0.f,0.f,0.f,0.f};
        c1 = MFMA16(kf.h0, qf.h0, c1);
        c2 = MFMA16(kf.h0, qf.l0, c2);
        c3 = MFMA16(kf.l0, qf.h0, c3);
        c1 = MFMA16(kf.h1, qf.h1, c1);
        c2 = MFMA16(kf.h1, qf.l1, c2);
        c3 = MFMA16(kf.l1, qf.h1, c3);
        union { u16 u[4]; uint2 v2; } PH, PL;
        #pragma unroll
        for (int r = 0; r < 4; r++){
          float x = __builtin_exp2f(c1[r] + c2[r] + c3[r]);
          u16 hb = f2bf(x);
          float hf = bf2f(hb);
          PH.u[r] = hb;
          PL.u[r] = f2bf(x - hf);
        }
        *(uint2*)(PhB + (jt*16 + l15)*80 + msub*32 + g*8) = PH.v2;
        *(uint2*)(PlB + (jt*16 + l15)*80 + msub*32 + g*8) = PL.v2;
      }
    }
    #pragma unroll
    for (int jt = 0; jt < 2; jt++){
      bf16x8 pf_h = *(const bf16x8*)(PhB + (jt*16 + l15)*80 + g*16);
      bf16x8 pf_l = *(const bf16x8*)(PlB + (jt*16 + l15)*80 + g*16);
      #pragma unroll
      for (int es = 0; es < 4; es++){
        gacc[jt][es] = MFMA16(vfh[es], pf_h, gacc[jt][es]);
        gacc[jt][es] = MFMA16(vfh[es], pf_l, gacc[jt][es]);
        gacc[jt][es] = MFMA16(vfl[es], pf_h, gacc[jt][es]);
      }
    }
  }
  LDS_FENCE();
  float* GT = (float*)smem;
  #pragma unroll
  for (int jt = 0; jt < 2; jt++)
    #pragma unroll
    for (int es = 0; es < 4; es++)
      #pragma unroll
      for (int r = 0; r < 4; r++)
        GT[(es*16 + g*4 + r)*32 + jt*16 + l15] = gacc[jt][es][r];
  LDS_FENCE();
  float* gb = gsp + ((size_t)iz*B_ + b)*E_*HW_;
  #pragma unroll
  for (int itx = 0; itx < 8; itx++){
    int n = (itx*64 + lane)*4;
    f32x4 vv = *(const f32x4*)&GT[n];
    int e = n >> 5, jj = n & 31;
    *(f32x4*)&gb[(size_t)e*HW_ + j0 + jj] = vv;
  }
}

// ---- gs = sum of 9 gsp partials ----
__global__ __launch_bounds__(256) void k_gsum9(const float* __restrict__ gsp, float* __restrict__ gs){
  const size_t N = (size_t)B_*E_*HW_;
  size_t n = ((size_t)blockIdx.x*256 + threadIdx.x)*4;
  f32x4 s = *(const f32x4*)(gsp + n);
  #pragma unroll
  for (int p = 1; p < 9; p++) s += *(const f32x4*)(gsp + (size_t)p*N + n);
  *(f32x4*)(gs + n) = s;
}

// ---- gsout[c,s] = sum_e watt[c,e]*gs[e,s] + batt[c]; 32 c-rows/block ----
__global__ __launch_bounds__(256) void k_gsout3(const float* __restrict__ gs,
    const float* __restrict__ watt, const float* __restrict__ batt,
    float* __restrict__ gsout){
  int b = blockIdx.x; int sc = blockIdx.y; int cc0 = blockIdx.z * 32;
  int s = sc*256 + threadIdx.x;
  const float* gb = gs + (size_t)b*E_*HW_ + s;
  float acc[32];
  #pragma unroll
  for (int x = 0; x < 32; x++) acc[x] = 0.f;
  for (int e = 0; e < E_; e++){
    float gv = gb[(size_t)e*HW_];
    #pragma unroll
    for (int x = 0; x < 32; x++) acc[x] += watt[(cc0+x)*E_ + e] * gv;   // uniform -> s_load
  }
  float* ob = gsout + (size_t)b*SB_ + (size_t)cc0*HW_ + s;
  #pragma unroll
  for (int x = 0; x < 32; x++) ob[(size_t)x*HW_] = acc[x] + batt[cc0 + x];
}

// ---- final: gc via MFMA with bf16-only attc (2-MFMA chains), fused elementwise. ----
// grid (B, 144, 4): 4 j-tiles per wave.
__global__ __launch_bounds__(64) void k_final7(const float* __restrict__ f,
    const u16* __restrict__ ath,
    float* __restrict__ inout){
  int b = blockIdx.x; int s0 = blockIdx.y*16; int z = blockIdx.z;
  int lane = threadIdx.x; int l15 = lane & 15, g = lane >> 4;
  const float* fb = f + (size_t)b*SB_;
  bf16x8 Ah[8], Al[8];
  const float* arow = fb + (size_t)(s0 + l15)*C_;
  #pragma unroll
  for (int ks = 0; ks < 8; ks++){
    int cbase = ks*32 + g*8;
    float4 f4a = *(const float4*)&arow[cbase];
    float4 f4b = *(const float4*)&arow[cbase + 4];
    float fe[8] = {f4a.x, f4a.y, f4a.z, f4a.w, f4b.x, f4b.y, f4b.z, f4b.w};
    union { u16 u[8]; bf16x8 v; } H, L;
    #pragma unroll
    for (int e = 0; e < 8; e++){
      u16 hb = f2bf(fe[e]);
      H.u[e] = hb;
      L.u[e] = f2bf(fe[e] - bf2f(hb));
    }
    Ah[ks] = H.v; Al[ks] = L.v;
  }
  const u16* abz_h = ath + (size_t)b*65536;
  f32x4 acc[4];
  #pragma unroll
  for (int q = 0; q < 4; q++) acc[q] = (f32x4){0.f,0.f,0.f,0.f};
  #pragma unroll
  for (int q = 0; q < 4; q++){
    int jt = z*4 + q;
    #pragma unroll
    for (int ks = 0; ks < 8; ks++){
      bf16x8 Bh = *(const bf16x8*)(abz_h + ((size_t)jt*8 + ks)*512 + (size_t)lane*8);
      acc[q] = MFMA16(Ah[ks], Bh, acc[q]);
      acc[q] = MFMA16(Al[ks], Bh, acc[q]);
    }
  }
  float* ob = inout + (size_t)b*SB_;
  #pragma unroll
  for (int q = 0; q < 4; q++){
    #pragma unroll
    for (int r = 0; r < 4; r++){
      int p = s0 + g*4 + r;
      int j = (z*4+q)*16 + l15;
      size_t n = (size_t)p*C_ + j;
      float fx = fb[n];
      float gso = ob[n];
      ob[n] = acc[q][r] * fx * (gso + 1.f);
    }
  }
}

extern "C" void kernel_launch(void* const* d_in, const int* in_sizes, int n_in,
                              void* d_out, int out_size, void* d_ws, size_t ws_size,
                              hipStream_t stream){
  const float* f    = (const float*)d_in[0];
  const float* wq1  = (const float*)d_in[1];
  const float* bq1  = (const float*)d_in[2];
  const float* wk1  = (const float*)d_in[3];
  const float* bk1  = (const float*)d_in[4];
  const float* wq2  = (const float*)d_in[5];
  const float* bq2  = (const float*)d_in[6];
  const float* wk2  = (const float*)d_in[7];
  const float* bk2  = (const float*)d_in[8];
  const float* wv2  = (const float*)d_in[9];
  const float* bv2  = (const float*)d_in[10];
  const float* watt = (const float*)d_in[11];
  const float* batt = (const float*)d_in[12];
  float* out = (float*)d_out;
  char* W = (char*)d_ws;

  // byte offsets (16B aligned); total = 64,380,928 B (~61.4 MiB)
  float* gap   = (float*)(W + 0);          //     8192
  u16*   ath   = (u16*)  (W + 8192);       //  1048576
  float* lpart = (float*)(W + 2105344);    //   663552 (9 x B x HW)
  float* rl    = (float*)(W + 2768896);    //    73728
  float* gsp   = (float*)(W + 2842624);    // 42467328 (9 x B x E x HW)
  float* gs    = (float*)(W + 45309952);   //  4718592
  u16* qh  = (u16*)(W + 50028544);         //  2359296 each below
  u16* qlo = (u16*)(W + 52387840);
  u16* kh  = (u16*)(W + 54747136);
  u16* klo = (u16*)(W + 57106432);
  u16* vh  = (u16*)(W + 59465728);
  u16* vlo = (u16*)(W + 61825024);
  u16* wbh = (u16*)(W + 64184320);         //    98304
  u16* wbl = (u16*)(W + 64282624);         //    98304

  k_gap   <<<B_*C_,             256, 0, stream>>>(f, gap);
  k_attc4 <<<B_*C_,             256, 0, stream>>>(gap, wq1, bq1, wk1, bk1, ath);
  k_wcvt  <<<192,               256, 0, stream>>>(wq2, wk2, wv2, wbh, wbl);
  k_proj6 <<<dim3(B_, 144, 6),   64, 0, stream>>>(f, wbh, wbl, bq2, bk2, bv2,
                                                  qh, qlo, kh, klo, vh, vlo);
  k_stats6<<<dim3(B_, 72, 9),    64, 0, stream>>>(qh, qlo, kh, klo, lpart);
  k_rli9  <<<B_*HW_/256,        256, 0, stream>>>(lpart, rl);
  k_vscale<<<576,               256, 0, stream>>>(rl, vh, vlo);
  k_gs13  <<<dim3(B_, 72, 9),    64, 0, stream>>>(qh, qlo, kh, klo, vh, vlo, gsp);
  k_gsum9 <<<B_*E_*HW_/1024,    256, 0, stream>>>(gsp, gs);
  k_gsout3<<<dim3(B_, 9, 8),    256, 0, stream>>>(gs, watt, batt, out);
  k_final7<<<dim3(B_, 144, 4),   64, 0, stream>>>(f, ath, out);
}

// Round 17
// 163.457 us; speedup vs baseline: 1.0364x; 1.0258x over previous
//
#include <hip/hip_runtime.h>

#define B_ 8
#define C_ 256
#define HW_ 2304
#define E_ 64
#define SB_ (C_*HW_)  // 589824 floats per batch
#define LOG2E_ 1.44269504088896340736f

typedef unsigned short u16;
typedef __attribute__((ext_vector_type(8))) __bf16 bf16x8;
typedef __attribute__((ext_vector_type(4))) float f32x4;
#define MFMA16(a,b,c) __builtin_amdgcn_mfma_f32_16x16x32_bf16(a,b,c,0,0,0)

// per-wave LDS write->read ordering (single-wave blocks; vmcnt untouched)
#define LDS_FENCE() do { asm volatile("s_waitcnt lgkmcnt(0)" ::: "memory"); \
                         __builtin_amdgcn_sched_barrier(0); } while(0)

// fp32 -> bf16 RNE via integer ops (compiler-schedulable scalar path)
static __device__ inline u16 f2bf(float x){
  unsigned u = __builtin_bit_cast(unsigned, x);
  u += 0x7FFFu + ((u >> 16) & 1u);
  return (u16)(u >> 16);
}
static __device__ inline float bf2f(u16 h){
  unsigned u = ((unsigned)h) << 16;
  return __builtin_bit_cast(float, u);
}

// Fragment-contiguous layouts (u16 units), lane = g*16 + l15:
//  Q/K:  (tile*2 + kc)*512 + lane*8 + u ; tile = b*144 + pos/16, value (pos=tile*16+l15, e=kc*32+g*8+u)
//  V:    ((b*72 + ic)*4 + es)*512 + lane*8 + u ; value (e=es*16+l15, i=ic*32+g*8+u)
//  attc: ((b*16 + jt)*8 + kc)*512 + lane*8 + u ; value (j=jt*16+l15, i=kc*32+g*8+u)
//  W:    ((mz*4 + m)*8 + kc)*512 + lane*8 + u  ; value (e=m*16+l15, c=kc*32+g*8+u)
// NOTE: K (mz==1) is pre-scaled by log2e so softmax uses native exp2 (v_exp_f32).
// NOTE: attc stored hi-only (softmax columns sum to 1 -> bf16-only error <= ~2e-3).

struct KFrag { bf16x8 h0, h1, l0, l1; };
static __device__ __forceinline__ KFrag ldfrag(const u16* __restrict__ ph,
                                               const u16* __restrict__ pl,
                                               size_t tile, int lane){
  KFrag q;
  q.h0 = *(const bf16x8*)(ph + (tile*2+0)*512 + (size_t)lane*8);
  q.h1 = *(const bf16x8*)(ph + (tile*2+1)*512 + (size_t)lane*8);
  q.l0 = *(const bf16x8*)(pl + (tile*2+0)*512 + (size_t)lane*8);
  q.l1 = *(const bf16x8*)(pl + (tile*2+1)*512 + (size_t)lane*8);
  return q;
}

// ---- GAP: mean over HW per (b,c) ----
__global__ __launch_bounds__(256) void k_gap(const float* __restrict__ f, float* __restrict__ gap){
  int bc = blockIdx.x;
  const float* row = f + (size_t)bc * HW_;
  float s = 0.f;
  for (int i = threadIdx.x; i < HW_; i += 256) s += row[i];
  #pragma unroll
  for (int off = 32; off; off >>= 1) s += __shfl_down(s, off);
  __shared__ float red[4];
  int lane = threadIdx.x & 63, wv = threadIdx.x >> 6;
  if (lane == 0) red[wv] = s;
  __syncthreads();
  if (threadIdx.x == 0) gap[bc] = (red[0]+red[1]+red[2]+red[3]) * (1.0f/HW_);
}

// ---- conv1d(k=3)+sigmoid, rank-1 scores, softmax over i -> bf16 (hi only) B-frag layout ----
__global__ __launch_bounds__(256) void k_attc4(const float* __restrict__ gap,
    const float* __restrict__ wq1, const float* __restrict__ bq1,
    const float* __restrict__ wk1, const float* __restrict__ bk1,
    u16* __restrict__ ath){
  int b = blockIdx.x >> 8;
  int j = blockIdx.x & 255;
  int i = threadIdx.x;
  const float* g = gap + b*C_;
  float gm1 = (i > 0)      ? g[i-1] : 0.f;
  float g0  = g[i];
  float gp1 = (i < C_-1)   ? g[i+1] : 0.f;
  float keyv = wk1[0]*gm1 + wk1[1]*g0 + wk1[2]*gp1 + bk1[0];
  keyv = 1.f/(1.f+__expf(-keyv));
  float qm1 = (j > 0)      ? g[j-1] : 0.f;
  float q0  = g[j];
  float qp1 = (j < C_-1)   ? g[j+1] : 0.f;
  float qv = wq1[0]*qm1 + wq1[1]*q0 + wq1[2]*qp1 + bq1[0];
  qv = 1.f/(1.f+__expf(-qv));
  float s = keyv * qv;
  __shared__ float red[8];
  int wv = i >> 6, ln = i & 63;
  float m = s;
  #pragma unroll
  for (int off = 32; off; off >>= 1) m = fmaxf(m, __shfl_xor(m, off));
  if (ln == 0) red[wv] = m;
  __syncthreads();
  float mx = fmaxf(fmaxf(red[0], red[1]), fmaxf(red[2], red[3]));
  float e = __expf(s - mx);
  float sm = e;
  #pragma unroll
  for (int off = 32; off; off >>= 1) sm += __shfl_xor(sm, off);
  if (ln == 0) red[4 + wv] = sm;
  __syncthreads();
  float sum = (red[4] + red[5]) + (red[6] + red[7]);
  float x = e / sum;
  size_t o = (((size_t)b*16 + (j>>4))*8 + (i>>5))*512 + (((i&31)>>3)*16 + (j&15))*8 + (i&7);
  ath[o] = f2bf(x);
}

// ---- convert wq2/wk2/wv2 -> bf16 hi/lo A-frag layout; K pre-scaled by log2e ----
__global__ __launch_bounds__(256) void k_wcvt(const float* __restrict__ wq,
    const float* __restrict__ wk, const float* __restrict__ wv,
    u16* __restrict__ wbh, u16* __restrict__ wbl){
  int n = blockIdx.x*256 + threadIdx.x;     // 0..49151
  int mz = n >> 14; int idx = n & 16383;
  int e = idx >> 8, c = idx & 255;
  const float* w = (mz==0) ? wq : ((mz==1) ? wk : wv);
  float x = w[idx] * ((mz==1) ? LOG2E_ : 1.0f);
  u16 hb = f2bf(x);
  size_t widx = (((size_t)mz*4 + (e>>4))*8 + (c>>5))*512 + (((c&31)>>3)*16 + (e&15))*8 + (c&7);
  wbh[widx] = hb;
  wbl[widx] = f2bf(x - bf2f(hb));
}

// ---- q/k/v projections via MFMA. 1 wave per (b, p-tile 16, matrix x e-half). ----
__global__ __launch_bounds__(64) void k_proj6(const float* __restrict__ f,
    const u16* __restrict__ wbh, const u16* __restrict__ wbl,
    const float* __restrict__ bq, const float* __restrict__ bk, const float* __restrict__ bv,
    u16* __restrict__ qh, u16* __restrict__ qlo,
    u16* __restrict__ kh, u16* __restrict__ klo,
    u16* __restrict__ vh, u16* __restrict__ vlo){
  int b = blockIdx.x; int p0 = blockIdx.y*16;
  int mz = blockIdx.z >> 1, mh = blockIdx.z & 1;
  int lane = threadIdx.x; int l15 = lane & 15, g = lane >> 4;
  const float* fb = f + (size_t)b*SB_ + p0 + l15;
  const u16* wh = wbh + (size_t)mz*16384;
  const u16* wl = wbl + (size_t)mz*16384;
  const float* bi = (mz==0) ? bq : ((mz==1) ? bk : bv);
  const float bsc = (mz==1) ? LOG2E_ : 1.0f;
  f32x4 c1[2], c2[2], c3[2];
  #pragma unroll
  for (int m = 0; m < 2; m++){
    c1[m] = (f32x4){0.f,0.f,0.f,0.f};
    c2[m] = (f32x4){0.f,0.f,0.f,0.f};
    c3[m] = (f32x4){0.f,0.f,0.f,0.f};
  }
  #pragma unroll
  for (int ks = 0; ks < 8; ks++){
    int cb = ks*32 + g*8;
    float fe[8];
    #pragma unroll
    for (int u = 0; u < 8; u++) fe[u] = fb[(size_t)(cb + u)*HW_];
    union { u16 u[8]; bf16x8 v; } FH, FL;
    #pragma unroll
    for (int u = 0; u < 8; u++){
      u16 hb = f2bf(fe[u]);
      FH.u[u] = hb;
      FL.u[u] = f2bf(fe[u] - bf2f(hb));
    }
    #pragma unroll
    for (int ml = 0; ml < 2; ml++){
      int m = mh*2 + ml;
      bf16x8 awh = *(const bf16x8*)(wh + ((size_t)m*8 + ks)*512 + (size_t)lane*8);
      bf16x8 awl = *(const bf16x8*)(wl + ((size_t)m*8 + ks)*512 + (size_t)lane*8);
      c1[ml] = MFMA16(awh, FH.v, c1[ml]);
      c2[ml] = MFMA16(awh, FL.v, c2[ml]);
      c3[ml] = MFMA16(awl, FH.v, c3[ml]);
    }
  }
  if (mz < 2){
    u16* ohb = (mz==0 ? qh : kh);
    u16* olb = (mz==0 ? qlo: klo);
    size_t tb = ((size_t)b*144 + blockIdx.y)*2;
    #pragma unroll
    for (int ml = 0; ml < 2; ml++){
      int m = mh*2 + ml;
      union { u16 u[4]; uint2 v2; } H, L;
      #pragma unroll
      for (int r = 0; r < 4; r++){
        int e = m*16 + g*4 + r;
        float x = c1[ml][r] + c2[ml][r] + c3[ml][r] + bi[e]*bsc;
        u16 hb = f2bf(x);
        H.u[r] = hb;
        L.u[r] = f2bf(x - bf2f(hb));
      }
      int kc = mh;
      int gc = ml*2 + (g >> 1);
      int ub = (g & 1)*4;
      size_t idx = (tb + kc)*512 + (gc*16 + l15)*8 + ub;
      *(uint2*)(ohb + idx) = H.v2;
      *(uint2*)(olb + idx) = L.v2;
    }
  } else {
    int ic = blockIdx.y >> 1;
    int half = blockIdx.y & 1;
    int gg = half*2 + (l15 >> 3);
    int uu = l15 & 7;
    size_t vb0 = ((size_t)b*72 + ic)*4;
    #pragma unroll
    for (int ml = 0; ml < 2; ml++){
      int m = mh*2 + ml;
      #pragma unroll
      for (int r = 0; r < 4; r++){
        int e = m*16 + g*4 + r;
        float x = c1[ml][r] + c2[ml][r] + c3[ml][r] + bi[e];
        u16 hb = f2bf(x);
        size_t idx = (vb0 + m)*512 + (gg*16 + (g*4 + r))*8 + uu;
        vh[idx] = hb;
        vlo[idx] = f2bf(x - bf2f(hb));
      }
    }
  }
}

// ---- pass 1: partial row sums l_i = sum_j exp2(s'), i-tile 32, j range 256 (16 tiles). ----
// grid (B, 72, 9)
__global__ __launch_bounds__(64,2) void k_stats6(
    const u16* __restrict__ qh, const u16* __restrict__ qlo,
    const u16* __restrict__ kh, const u16* __restrict__ klo,
    float* __restrict__ lpart){
  int b = blockIdx.x; int it0 = blockIdx.y; int jz = blockIdx.z;
  int lane = threadIdx.x; int l15 = lane & 15, g = lane >> 4;
  const size_t b144 = (size_t)b*144;
  KFrag kf0 = ldfrag(kh, klo, b144 + it0*2,     lane);
  KFrag kf1 = ldfrag(kh, klo, b144 + it0*2 + 1, lane);
  float lsum[8];
  #pragma unroll
  for (int x = 0; x < 8; x++) lsum[x] = 0.f;
  size_t qb0 = b144 + jz*16;
  #pragma unroll
  for (int t = 0; t < 16; t++){
    KFrag q = ldfrag(qh, qlo, qb0 + t, lane);
    #pragma unroll
    for (int isub = 0; isub < 2; isub++){
      const KFrag& kf = isub ? kf1 : kf0;
      f32x4 c1 = {0.f,0.f,0.f,0.f}, c2 = {0.f,0.f,0.f,0.f}, c3 = {0.f,0.f,0.f,0.f};
      c1 = MFMA16(kf.h0, q.h0, c1);
      c2 = MFMA16(kf.h0, q.l0, c2);
      c3 = MFMA16(kf.l0, q.h0, c3);
      c1 = MFMA16(kf.h1, q.h1, c1);
      c2 = MFMA16(kf.h1, q.l1, c2);
      c3 = MFMA16(kf.l1, q.h1, c3);
      #pragma unroll
      for (int r = 0; r < 4; r++) lsum[isub*4+r] += __builtin_exp2f(c1[r] + c2[r] + c3[r]);
    }
  }
  #pragma unroll
  for (int mk = 1; mk < 16; mk <<= 1){
    #pragma unroll
    for (int x = 0; x < 8; x++) lsum[x] += __shfl_xor(lsum[x], mk);
  }
  if (l15 == 0){
    float* lp = lpart + ((size_t)jz*B_ + b)*HW_ + it0*32;
    #pragma unroll
    for (int isub = 0; isub < 2; isub++)
      #pragma unroll
      for (int r = 0; r < 4; r++) lp[isub*16 + g*4 + r] = lsum[isub*4+r];
  }
}

// ---- rl = 1/(sum of 9 partials) ----
__global__ __launch_bounds__(256) void k_rli9(const float* __restrict__ lpart, float* __restrict__ rl){
  int i = blockIdx.x*256 + threadIdx.x;
  const int BH = B_*HW_;
  float s = 0.f;
  #pragma unroll
  for (int p = 0; p < 9; p++) s += lpart[(size_t)p*BH + i];
  rl[i] = 1.0f / s;
}

// ---- pass 2: partial GS, j-tile 32, i range 256 (8 chunks). R10-exact structure: ----
// fences, double-buffered P, rolled (unroll 2) loop, rl multiply AFTER exp2. grid (B, 72, 9).
__global__ __launch_bounds__(64) void k_gs7r(
    const u16* __restrict__ qh, const u16* __restrict__ qlo,
    const u16* __restrict__ kh, const u16* __restrict__ klo,
    const u16* __restrict__ vh, const u16* __restrict__ vlo,
    const float* __restrict__ rl, float* __restrict__ gsp){
  int b = blockIdx.x; int jt0 = blockIdx.y; int iz = blockIdx.z;
  int j0 = jt0*32;
  int lane = threadIdx.x; int l15 = lane & 15, g = lane >> 4;
  __shared__ __align__(16) char smem[10240];
  const size_t b144 = (size_t)b*144;
  KFrag qf0 = ldfrag(qh, qlo, b144 + jt0*2,     lane);
  KFrag qf1 = ldfrag(qh, qlo, b144 + jt0*2 + 1, lane);
  f32x4 gacc[2][4];
  #pragma unroll
  for (int jt = 0; jt < 2; jt++)
    #pragma unroll
    for (int es = 0; es < 4; es++) gacc[jt][es] = (f32x4){0.f,0.f,0.f,0.f};
  const float* rlb = rl + b*HW_;
  #pragma unroll 2
  for (int ic = 0; ic < 8; ic++){
    int i0c = iz*256 + ic*32;
    // V A-frags (dense 1KB loads), issued early, consumed after the fence
    bf16x8 vfh[4], vfl[4];
    size_t vc = ((size_t)b*72 + iz*8 + ic)*4;
    #pragma unroll
    for (int es = 0; es < 4; es++){
      vfh[es] = *(const bf16x8*)(vh  + (vc+es)*512 + (size_t)lane*8);
      vfl[es] = *(const bf16x8*)(vlo + (vc+es)*512 + (size_t)lane*8);
    }
    char* PhB = smem + (ic & 1)*2560;
    char* PlB = smem + 5120 + (ic & 1)*2560;
    #pragma unroll
    for (int msub = 0; msub < 2; msub++){
      KFrag kf = ldfrag(kh, klo, b144 + iz*16 + ic*2 + msub, lane);
      f32x4 rlv = *(const f32x4*)&rlb[i0c + msub*16 + g*4];
      #pragma unroll
      for (int jt = 0; jt < 2; jt++){
        const KFrag& qf = jt ? qf1 : qf0;
        f32x4 c1 = {0.f,0.f,0.f,0.f}, c2 = {0.f,0.f,0.f,0.f}, c3 = {0.f,0.f,0.f,0.f};
        c1 = MFMA16(kf.h0, qf.h0, c1);
        c2 = MFMA16(kf.h0, qf.l0, c2);
        c3 = MFMA16(kf.l0, qf.h0, c3);
        c1 = MFMA16(kf.h1, qf.h1, c1);
        c2 = MFMA16(kf.h1, qf.l1, c2);
        c3 = MFMA16(kf.l1, qf.h1, c3);
        union { u16 u[4]; uint2 v2; } PH, PL;
        #pragma unroll
        for (int r = 0; r < 4; r++){
          float x = __builtin_exp2f(c1[r] + c2[r] + c3[r]) * rlv[r];
          u16 hb = f2bf(x);
          float hf = bf2f(hb);
          PH.u[r] = hb;
          PL.u[r] = f2bf(x - hf);
        }
        *(uint2*)(PhB + (jt*16 + l15)*80 + msub*32 + g*8) = PH.v2;
        *(uint2*)(PlB + (jt*16 + l15)*80 + msub*32 + g*8) = PL.v2;
      }
    }
    LDS_FENCE();
    #pragma unroll
    for (int jt = 0; jt < 2; jt++){
      bf16x8 pf_h = *(const bf16x8*)(PhB + (jt*16 + l15)*80 + g*16);
      bf16x8 pf_l = *(const bf16x8*)(PlB + (jt*16 + l15)*80 + g*16);
      #pragma unroll
      for (int es = 0; es < 4; es++){
        gacc[jt][es] = MFMA16(vfh[es], pf_h, gacc[jt][es]);
        gacc[jt][es] = MFMA16(vfh[es], pf_l, gacc[jt][es]);
        gacc[jt][es] = MFMA16(vfl[es], pf_h, gacc[jt][es]);
      }
    }
  }
  // epilogue: transpose gacc through LDS -> full-line dwordx4 stores
  LDS_FENCE();
  float* GT = (float*)smem;
  #pragma unroll
  for (int jt = 0; jt < 2; jt++)
    #pragma unroll
    for (int es = 0; es < 4; es++)
      #pragma unroll
      for (int r = 0; r < 4; r++)
        GT[(es*16 + g*4 + r)*32 + jt*16 + l15] = gacc[jt][es][r];
  LDS_FENCE();
  float* gb = gsp + ((size_t)iz*B_ + b)*E_*HW_;
  #pragma unroll
  for (int itx = 0; itx < 8; itx++){
    int n = (itx*64 + lane)*4;
    f32x4 vv = *(const f32x4*)&GT[n];
    int e = n >> 5, jj = n & 31;
    *(f32x4*)&gb[(size_t)e*HW_ + j0 + jj] = vv;
  }
}

// ---- gs = sum of 9 gsp partials ----
__global__ __launch_bounds__(256) void k_gsum9(const float* __restrict__ gsp, float* __restrict__ gs){
  const size_t N = (size_t)B_*E_*HW_;
  size_t n = ((size_t)blockIdx.x*256 + threadIdx.x)*4;
  f32x4 s = *(const f32x4*)(gsp + n);
  #pragma unroll
  for (int p = 1; p < 9; p++) s += *(const f32x4*)(gsp + (size_t)p*N + n);
  *(f32x4*)(gs + n) = s;
}

// ---- gsout[c,s] = sum_e watt[c,e]*gs[e,s] + batt[c]; 32 c-rows/block ----
__global__ __launch_bounds__(256) void k_gsout3(const float* __restrict__ gs,
    const float* __restrict__ watt, const float* __restrict__ batt,
    float* __restrict__ gsout){
  int b = blockIdx.x; int sc = blockIdx.y; int cc0 = blockIdx.z * 32;
  int s = sc*256 + threadIdx.x;
  const float* gb = gs + (size_t)b*E_*HW_ + s;
  float acc[32];
  #pragma unroll
  for (int x = 0; x < 32; x++) acc[x] = 0.f;
  for (int e = 0; e < E_; e++){
    float gv = gb[(size_t)e*HW_];
    #pragma unroll
    for (int x = 0; x < 32; x++) acc[x] += watt[(cc0+x)*E_ + e] * gv;   // uniform -> s_load
  }
  float* ob = gsout + (size_t)b*SB_ + (size_t)cc0*HW_ + s;
  #pragma unroll
  for (int x = 0; x < 32; x++) ob[(size_t)x*HW_] = acc[x] + batt[cc0 + x];
}

// ---- final: gc via MFMA with bf16-only attc (2-MFMA chains), fused elementwise. ----
// grid (B, 144, 4): 4 j-tiles per wave.
__global__ __launch_bounds__(64) void k_final7(const float* __restrict__ f,
    const u16* __restrict__ ath,
    float* __restrict__ inout){
  int b = blockIdx.x; int s0 = blockIdx.y*16; int z = blockIdx.z;
  int lane = threadIdx.x; int l15 = lane & 15, g = lane >> 4;
  const float* fb = f + (size_t)b*SB_;
  bf16x8 Ah[8], Al[8];
  const float* arow = fb + (size_t)(s0 + l15)*C_;
  #pragma unroll
  for (int ks = 0; ks < 8; ks++){
    int cbase = ks*32 + g*8;
    float4 f4a = *(const float4*)&arow[cbase];
    float4 f4b = *(const float4*)&arow[cbase + 4];
    float fe[8] = {f4a.x, f4a.y, f4a.z, f4a.w, f4b.x, f4b.y, f4b.z, f4b.w};
    union { u16 u[8]; bf16x8 v; } H, L;
    #pragma unroll
    for (int e = 0; e < 8; e++){
      u16 hb = f2bf(fe[e]);
      H.u[e] = hb;
      L.u[e] = f2bf(fe[e] - bf2f(hb));
    }
    Ah[ks] = H.v; Al[ks] = L.v;
  }
  const u16* abz_h = ath + (size_t)b*65536;
  f32x4 acc[4];
  #pragma unroll
  for (int q = 0; q < 4; q++) acc[q] = (f32x4){0.f,0.f,0.f,0.f};
  #pragma unroll
  for (int q = 0; q < 4; q++){
    int jt = z*4 + q;
    #pragma unroll
    for (int ks = 0; ks < 8; ks++){
      bf16x8 Bh = *(const bf16x8*)(abz_h + ((size_t)jt*8 + ks)*512 + (size_t)lane*8);
      acc[q] = MFMA16(Ah[ks], Bh, acc[q]);
      acc[q] = MFMA16(Al[ks], Bh, acc[q]);
    }
  }
  float* ob = inout + (size_t)b*SB_;
  #pragma unroll
  for (int q = 0; q < 4; q++){
    #pragma unroll
    for (int r = 0; r < 4; r++){
      int p = s0 + g*4 + r;
      int j = (z*4+q)*16 + l15;
      size_t n = (size_t)p*C_ + j;
      float fx = fb[n];
      float gso = ob[n];
      ob[n] = acc[q][r] * fx * (gso + 1.f);
    }
  }
}

extern "C" void kernel_launch(void* const* d_in, const int* in_sizes, int n_in,
                              void* d_out, int out_size, void* d_ws, size_t ws_size,
                              hipStream_t stream){
  const float* f    = (const float*)d_in[0];
  const float* wq1  = (const float*)d_in[1];
  const float* bq1  = (const float*)d_in[2];
  const float* wk1  = (const float*)d_in[3];
  const float* bk1  = (const float*)d_in[4];
  const float* wq2  = (const float*)d_in[5];
  const float* bq2  = (const float*)d_in[6];
  const float* wk2  = (const float*)d_in[7];
  const float* bk2  = (const float*)d_in[8];
  const float* wv2  = (const float*)d_in[9];
  const float* bv2  = (const float*)d_in[10];
  const float* watt = (const float*)d_in[11];
  const float* batt = (const float*)d_in[12];
  float* out = (float*)d_out;
  char* W = (char*)d_ws;

  // byte offsets (16B aligned); total = 64,380,928 B (~61.4 MiB)
  float* gap   = (float*)(W + 0);          //     8192
  u16*   ath   = (u16*)  (W + 8192);       //  1048576
  float* lpart = (float*)(W + 2105344);    //   663552 (9 x B x HW)
  float* rl    = (float*)(W + 2768896);    //    73728
  float* gsp   = (float*)(W + 2842624);    // 42467328 (9 x B x E x HW)
  float* gs    = (float*)(W + 45309952);   //  4718592
  u16* qh  = (u16*)(W + 50028544);         //  2359296 each below
  u16* qlo = (u16*)(W + 52387840);
  u16* kh  = (u16*)(W + 54747136);
  u16* klo = (u16*)(W + 57106432);
  u16* vh  = (u16*)(W + 59465728);
  u16* vlo = (u16*)(W + 61825024);
  u16* wbh = (u16*)(W + 64184320);         //    98304
  u16* wbl = (u16*)(W + 64282624);         //    98304

  k_gap   <<<B_*C_,             256, 0, stream>>>(f, gap);
  k_attc4 <<<B_*C_,             256, 0, stream>>>(gap, wq1, bq1, wk1, bk1, ath);
  k_wcvt  <<<192,               256, 0, stream>>>(wq2, wk2, wv2, wbh, wbl);
  k_proj6 <<<dim3(B_, 144, 6),   64, 0, stream>>>(f, wbh, wbl, bq2, bk2, bv2,
                                                  qh, qlo, kh, klo, vh, vlo);
  k_stats6<<<dim3(B_, 72, 9),    64, 0, stream>>>(qh, qlo, kh, klo, lpart);
  k_rli9  <<<B_*HW_/256,        256, 0, stream>>>(lpart, rl);
  k_gs7r  <<<dim3(B_, 72, 9),    64, 0, stream>>>(qh, qlo, kh, klo, vh, vlo, rl, gsp);
  k_gsum9 <<<B_*E_*HW_/1024,    256, 0, stream>>>(gsp, gs);
  k_gsout3<<<dim3(B_, 9, 8),    256, 0, stream>>>(gs, watt, batt, out);
  k_final7<<<dim3(B_, 144, 4),   64, 0, stream>>>(f, ath, out);
}